// Round 1
// 373.698 us; speedup vs baseline: 1.1565x; 1.1565x over previous
//
#include <hip/hip_runtime.h>
#include <hip/hip_bf16.h>

#define HH 56
#define WW 56
#define HW 3136
#define CIN 256
#define COUT 512
#define NBATCH 32
#define EPS 1e-5f
#define DW_TH 4.0f
#define PW_TH 1e-3f

#define CG 32            // channels per dw block
#define CPITCH 508       // floats per channel in dw LDS (9*56=504 + pad 4)

typedef __attribute__((ext_vector_type(8))) short s16x8;
typedef __attribute__((ext_vector_type(4))) float f32x4;
typedef unsigned int u32;
typedef unsigned short u16;

__device__ __forceinline__ void async_copy16(void* lds, const void* g) {
    __builtin_amdgcn_global_load_lds((const __attribute__((address_space(1))) unsigned int*)g,
                                     (__attribute__((address_space(3))) unsigned int*)lds,
                                     16, 0, 0);
}

__device__ __forceinline__ u16 bf16_bits(float f) {
    __hip_bfloat16 h = __float2bfloat16(f);
    union { __hip_bfloat16 h; u16 u; } cv; cv.h = h; return cv.u;
}

// ---------------- prep: W fp32 -> bf16, fold BN2+bias into (scale,shift), zero max buffers ----------------
__global__ __launch_bounds__(256) void prep_kernel(
    const float* __restrict__ pww, const float* __restrict__ pwb,
    const float* __restrict__ g2, const float* __restrict__ b2,
    const float* __restrict__ m2, const float* __restrict__ v2,
    u16* __restrict__ wb, float2* __restrict__ scsh,
    u32* __restrict__ omax, u32* __restrict__ dwmax)
{
    const int gid = blockIdx.x * 256 + threadIdx.x;     // 16384 threads
    const int base = gid * 8;                           // covers 131072 = COUT*CIN
    const float4 a = *(const float4*)(pww + base);
    const float4 b = *(const float4*)(pww + base + 4);
    union { u16 u[8]; s16x8 v; } pk;
    pk.u[0] = bf16_bits(a.x); pk.u[1] = bf16_bits(a.y);
    pk.u[2] = bf16_bits(a.z); pk.u[3] = bf16_bits(a.w);
    pk.u[4] = bf16_bits(b.x); pk.u[5] = bf16_bits(b.y);
    pk.u[6] = bf16_bits(b.z); pk.u[7] = bf16_bits(b.w);
    *(s16x8*)(wb + base) = pk.v;
    omax[gid] = 0u;                                     // NBATCH*COUT = 16384
    if (gid < NBATCH * CIN) dwmax[gid] = 0u;            // 8192
    if (gid < COUT) {
        const float sc = g2[gid] * rsqrtf(v2[gid] + EPS);
        const float sh = fmaf(-m2[gid], sc, b2[gid]) + pwb[gid] * sc;
        scsh[gid] = make_float2(sc, sh);
    }
}

// ---------------- dw: LDS-staged 3x3 depthwise + BN1 + ReLU -> y NHWC bf16 + per-(n,c) max ----------------
// block = (n, 7-row strip, 32-channel group); 2048 blocks x 256 threads; 63.5 KB LDS
__global__ __launch_bounds__(256) void dw_kernel(
    const float* __restrict__ x, const float* __restrict__ dww, const float* __restrict__ dwb,
    const float* __restrict__ g1, const float* __restrict__ b1,
    const float* __restrict__ m1, const float* __restrict__ v1,
    u16* __restrict__ y, u32* __restrict__ dwmax)
{
    __shared__ float xs[CG * CPITCH];   // [c][local row 0..8][px], rows = strip rows -1..+7

    const int bid = blockIdx.x;
    const int cg = bid & 7;             // channel group (8)
    const int hs = (bid >> 3) & 7;      // strip (8)
    const int n  = bid >> 6;            // batch (32)
    const int t  = threadIdx.x;

    const int g0     = hs * 7 - 1;                 // global row mapped to local slot 0
    const int gstart = (g0 < 0) ? 0 : g0;
    const int gend   = (hs * 7 + 7 > 55) ? 55 : hs * 7 + 7;
    const int nrows  = gend - gstart + 1;          // 8 or 9
    const int dst0   = gstart - g0;                // 1 iff hs==0 else 0
    const int cnt4   = nrows * 14;                 // float4s per channel span

    // zero clipped halo row
    if (hs == 0) {
        for (int i = t; i < CG * 14; i += 256) {
            const int c = i / 14, j = i - c * 14;
            *(float4*)&xs[c * CPITCH + j * 4] = make_float4(0.f, 0.f, 0.f, 0.f);
        }
    } else if (hs == 7) {
        for (int i = t; i < CG * 14; i += 256) {
            const int c = i / 14, j = i - c * 14;
            *(float4*)&xs[c * CPITCH + 8 * 56 + j * 4] = make_float4(0.f, 0.f, 0.f, 0.f);
        }
    }

    // coalesced staging: 2 channels in flight (128 threads each), 16 iterations
    {
        const float* gbase = x + (size_t)(n * CIN + cg * CG) * HW + gstart * 56;
        const int half = t >> 7;
        const int i4 = t & 127;
        for (int cc = 0; cc < 16; ++cc) {
            const int c = cc * 2 + half;
            if (i4 < cnt4) {
                const float4 v = *(const float4*)(gbase + (size_t)c * HW + i4 * 4);
                *(float4*)&xs[c * CPITCH + dst0 * 56 + i4 * 4] = v;
            }
        }
    }
    __syncthreads();

    // compute: thread = (local row r 0..6, channel c 0..31); 224 active
    const int r = t >> 5;
    const int c = t & 31;
    float vmax = 0.f;
    if (r < 7) {
        const int ch = cg * CG + c;
        const float* wp = dww + ch * 9;
        const float w00 = wp[0], w01 = wp[1], w02 = wp[2];
        const float w10 = wp[3], w11 = wp[4], w12 = wp[5];
        const float w20 = wp[6], w21 = wp[7], w22 = wp[8];
        const float sc = g1[ch] * rsqrtf(v1[ch] + EPS);
        const float sh = fmaf(-m1[ch], sc, b1[ch]) + dwb[ch] * sc;

        const float* rm = &xs[c * CPITCH + r * 56];        // global row (hs*7+r)-1
        const float* r0 = rm + 56;
        const float* rp = rm + 112;
        const int grow = hs * 7 + r;
        u16* yo = y + (size_t)(n * HW + grow * WW) * CIN + ch;

        float4 cm = *(const float4*)rm;
        float4 c0 = *(const float4*)r0;
        float4 cp = *(const float4*)rp;
        float lm = 0.f, l0 = 0.f, lp = 0.f;

        for (int chk = 0; chk < 14; ++chk) {
            float4 nm, n0, np;
            if (chk < 13) {
                nm = *(const float4*)(rm + 4 * chk + 4);
                n0 = *(const float4*)(r0 + 4 * chk + 4);
                np = *(const float4*)(rp + 4 * chk + 4);
            } else {
                nm = n0 = np = make_float4(0.f, 0.f, 0.f, 0.f);
            }
            float s0 = w00*lm   + w01*cm.x + w02*cm.y
                     + w10*l0   + w11*c0.x + w12*c0.y
                     + w20*lp   + w21*cp.x + w22*cp.y;
            float s1 = w00*cm.x + w01*cm.y + w02*cm.z
                     + w10*c0.x + w11*c0.y + w12*c0.z
                     + w20*cp.x + w21*cp.y + w22*cp.z;
            float s2 = w00*cm.y + w01*cm.z + w02*cm.w
                     + w10*c0.y + w11*c0.z + w12*c0.w
                     + w20*cp.y + w21*cp.z + w22*cp.w;
            float s3 = w00*cm.z + w01*cm.w + w02*nm.x
                     + w10*c0.z + w11*c0.w + w12*n0.x
                     + w20*cp.z + w21*cp.w + w22*np.x;
            const float v0 = fmaxf(fmaf(s0, sc, sh), 0.f);
            const float v1s = fmaxf(fmaf(s1, sc, sh), 0.f);
            const float v2s = fmaxf(fmaf(s2, sc, sh), 0.f);
            const float v3 = fmaxf(fmaf(s3, sc, sh), 0.f);
            vmax = fmaxf(fmaxf(vmax, fmaxf(v0, v1s)), fmaxf(v2s, v3));
            yo[(4 * chk + 0) * CIN] = bf16_bits(v0);
            yo[(4 * chk + 1) * CIN] = bf16_bits(v1s);
            yo[(4 * chk + 2) * CIN] = bf16_bits(v2s);
            yo[(4 * chk + 3) * CIN] = bf16_bits(v3);
            lm = cm.w; l0 = c0.w; lp = cp.w;
            cm = nm; c0 = n0; cp = np;
        }
    }
    // pair-reduce rows within wave (lanes 32 apart share c), then atomic
    vmax = fmaxf(vmax, __shfl_xor(vmax, 32));
    if ((t & 32) == 0)
        atomicMax(&dwmax[n * CIN + cg * CG + c], __float_as_uint(vmax));
}

// ---------------- pw v3: bf16 MFMA GEMM, O=256 x HW=112 tile, BK=32 double-buffered prefetch ----------------
// 4 waves x 64 O-rows each: 28 MFMA / 11 ds_read per wave per K-step.
// dw channel-cut applied via per-(n,k) AND-mask on the A fragments (replaces dwcut pass).
// grid: 1792 linear blocks, bijective XCD-chunked order (ot fastest within (n,hwt) per XCD).
__global__ __launch_bounds__(256, 2) void pw_kernel(
    const u16* __restrict__ y, const u16* __restrict__ wb,
    const float2* __restrict__ scsh, const u32* __restrict__ dwmax,
    float* __restrict__ out, u32* __restrict__ omax)
{
    __shared__ __align__(16) u16 Wt[2][256 * 32];   // [o][k], pitch 64B, 16 KB per buf
    __shared__ __align__(16) u16 Yt[2][112 * 32];   // [hw][k], pitch 64B, 7 KB per buf
    __shared__ __align__(16) u16 msk[CIN];          // 0xFFFF keep / 0 cut per k

    // 1792 = 8 XCD x 224; each XCD: 4 n x 28 hwt x 2 ot, ot fastest -> Y tile L2 reuse
    const int bid = blockIdx.x;
    const int g   = (bid & 7) * 224 + (bid >> 3);
    const int ot  = g & 1;
    const int r2  = g >> 1;                // 0..895
    const int hwt = r2 % 28;
    const int n   = r2 / 28;

    const int t = threadIdx.x;
    const int w = t >> 6;          // wave id 0..3
    const int l = t & 63;
    const int lo = l & 15, hi = l >> 4;

    const int o_blk  = ot * 256;
    const int hw_blk = n * HW + hwt * 112;

    const u16* wg = wb + (size_t)(o_blk + w * 64 + (l >> 2)) * CIN + (l & 3) * 8;
    const u16* yg = y  + (size_t)(hw_blk + (l >> 2)) * CIN + (l & 3) * 8;

    // dw channel-cut mask for this n (dwmax written by dw_kernel, device-coherent across launches)
    msk[t] = (__uint_as_float(dwmax[n * CIN + t]) >= DW_TH) ? (u16)0xFFFFu : (u16)0u;

    f32x4 acc[4][7];
#pragma unroll
    for (int s = 0; s < 4; ++s)
#pragma unroll
        for (int j = 0; j < 7; ++j) acc[s][j] = (f32x4){0.f, 0.f, 0.f, 0.f};

    // prologue: stage K-tile 0 into buffer 0
    {
        char* WtB = (char*)&Wt[0][0];
        char* YtB = (char*)&Yt[0][0];
#pragma unroll
        for (int i = 0; i < 4; ++i)
            async_copy16(WtB + (w * 64 + i * 16) * 64 + l * 16, wg + (size_t)(i * 16) * CIN);
        const int j0 = 2 * w;
        async_copy16(YtB + (j0 * 16) * 64 + l * 16, yg + (size_t)(j0 * 16) * CIN);
        if (j0 + 1 < 7)
            async_copy16(YtB + ((j0 + 1) * 16) * 64 + l * 16, yg + (size_t)((j0 + 1) * 16) * CIN);
    }
    __syncthreads();

#pragma unroll 2
    for (int tk = 0; tk < 8; ++tk) {
        const int cur = tk & 1;
        // prefetch next K-tile into other buffer BEFORE compute (T3-minimum: loads in flight across compute)
        if (tk < 7) {
            const int k1 = (tk + 1) * 32;
            char* WtB = (char*)&Wt[cur ^ 1][0];
            char* YtB = (char*)&Yt[cur ^ 1][0];
#pragma unroll
            for (int i = 0; i < 4; ++i)
                async_copy16(WtB + (w * 64 + i * 16) * 64 + l * 16, wg + k1 + (size_t)(i * 16) * CIN);
            const int j0 = 2 * w;
            async_copy16(YtB + (j0 * 16) * 64 + l * 16, yg + k1 + (size_t)(j0 * 16) * CIN);
            if (j0 + 1 < 7)
                async_copy16(YtB + ((j0 + 1) * 16) * 64 + l * 16, yg + k1 + (size_t)((j0 + 1) * 16) * CIN);
        }
        const char* WtB = (const char*)&Wt[cur][0];
        const char* YtB = (const char*)&Yt[cur][0];
        // mask chunk for k = tk*32 + hi*8 .. +7 (same-address broadcast within 16-lane groups)
        const s16x8 m8 = *(const s16x8*)((const char*)msk + tk * 64 + hi * 16);

        s16x8 af[4], bf[7];
#pragma unroll
        for (int s = 0; s < 4; ++s) {
            af[s] = *(const s16x8*)(WtB + (w * 64 + s * 16 + lo) * 64 + hi * 16);
            af[s] = af[s] & m8;    // zero cut channels (A-column zero == y-channel zero)
        }
#pragma unroll
        for (int j = 0; j < 7; ++j)
            bf[j] = *(const s16x8*)(YtB + (j * 16 + lo) * 64 + hi * 16);
#pragma unroll
        for (int s = 0; s < 4; ++s)
#pragma unroll
            for (int j = 0; j < 7; ++j)
                acc[s][j] = __builtin_amdgcn_mfma_f32_16x16x32_bf16(af[s], bf[j], acc[s][j], 0, 0, 0);
        __syncthreads();   // drains prefetch vmcnt + protects both buffers
    }

    // epilogue: C/D layout col=lane&15 (hw), row=(lane>>4)*4+reg (o)
#pragma unroll
    for (int s = 0; s < 4; ++s) {
#pragma unroll
        for (int r = 0; r < 4; ++r) {
            const int o = o_blk + w * 64 + s * 16 + hi * 4 + r;
            const float2 ss = scsh[o];
            float m = 0.f;
            float* op = out + (size_t)(n * COUT + o) * HW + hwt * 112 + lo;
#pragma unroll
            for (int j = 0; j < 7; ++j) {
                const float v = fmaxf(fmaf(acc[s][j][r], ss.x, ss.y), 0.f);
                op[j * 16] = v;
                m = fmaxf(m, v);
            }
            m = fmaxf(m, __shfl_xor(m, 1));
            m = fmaxf(m, __shfl_xor(m, 2));
            m = fmaxf(m, __shfl_xor(m, 4));
            m = fmaxf(m, __shfl_xor(m, 8));
            if (lo == 0) atomicMax(&omax[n * COUT + o], __float_as_uint(m));
        }
    }
}

// ---------------- pw channel cut fixup ----------------
__global__ __launch_bounds__(256) void pwcut_kernel(const u32* __restrict__ omax, float* __restrict__ out)
{
    const int b = blockIdx.x;   // n*COUT + o
    if (__uint_as_float(omax[b]) >= PW_TH) return;
    float* p = out + (size_t)b * HW;
    for (int i = threadIdx.x; i < HW; i += 256) p[i] = 0.0f;
}

extern "C" void kernel_launch(void* const* d_in, const int* in_sizes, int n_in,
                              void* d_out, int out_size, void* d_ws, size_t ws_size,
                              hipStream_t stream) {
    const float* x   = (const float*)d_in[0];
    const float* dww = (const float*)d_in[1];
    const float* dwb = (const float*)d_in[2];
    const float* g1  = (const float*)d_in[3];
    const float* b1  = (const float*)d_in[4];
    const float* m1  = (const float*)d_in[5];
    const float* v1  = (const float*)d_in[6];
    const float* pww = (const float*)d_in[7];
    const float* pwb = (const float*)d_in[8];
    const float* g2  = (const float*)d_in[9];
    const float* b2  = (const float*)d_in[10];
    const float* m2  = (const float*)d_in[11];
    const float* v2  = (const float*)d_in[12];
    float* out = (float*)d_out;

    // ws layout: [0,64K) pw omax; [64K,96K) dw max; [96K,100K) scsh; [128K,384K) W bf16; [1M,...) y NHWC bf16
    u32*    omax  = (u32*)d_ws;
    u32*    dwmax = (u32*)((char*)d_ws + (64 << 10));
    float2* scsh  = (float2*)((char*)d_ws + (96 << 10));
    u16*    wbf   = (u16*)((char*)d_ws + (128 << 10));
    u16*    y     = (u16*)((char*)d_ws + (1 << 20));

    prep_kernel<<<64, 256, 0, stream>>>(pww, pwb, g2, b2, m2, v2, wbf, scsh, omax, dwmax);
    dw_kernel<<<NBATCH * 8 * 8, 256, 0, stream>>>(x, dww, dwb, g1, b1, m1, v1, y, dwmax);
    pw_kernel<<<1792, 256, 0, stream>>>(y, wbf, scsh, dwmax, out, omax);
    pwcut_kernel<<<NBATCH * COUT, 256, 0, stream>>>(omax, out);
}

// Round 2
// 368.813 us; speedup vs baseline: 1.1718x; 1.0132x over previous
//
#include <hip/hip_runtime.h>
#include <hip/hip_bf16.h>

#define HW 3136
#define CIN 256
#define COUT 512
#define NBATCH 32
#define EPS 1e-5f
#define DW_TH 4.0f
#define PW_TH 1e-3f

#define DPITCH 564     // floats per channel in dw LDS: 10 rows * 56 + 4 pad (16B-aligned)

typedef __attribute__((ext_vector_type(8))) short s16x8;
typedef __attribute__((ext_vector_type(4))) float f32x4;
typedef unsigned int u32;
typedef unsigned short u16;

__device__ __forceinline__ void async_copy16(void* lds, const void* g) {
    __builtin_amdgcn_global_load_lds((const __attribute__((address_space(1))) unsigned int*)g,
                                     (__attribute__((address_space(3))) unsigned int*)lds,
                                     16, 0, 0);
}

__device__ __forceinline__ u16 bf16_bits(float f) {
    __hip_bfloat16 h = __float2bfloat16(f);
    union { __hip_bfloat16 h; u16 u; } cv; cv.h = h; return cv.u;
}

// ---------------- dw + prep fused ----------------
// blocks 0..1791: depthwise 3x3 + BN1 + ReLU -> y NHWC bf16 + per-(n,hs,c) partial max (no atomics)
//   block = (n, 8-row strip hs 0..6, 8-channel-group cg 0..7); 256 threads = 32 ch x 8 rows, all active
// blocks 1792..1855: prep (W fp32->bf16, fold BN2+bias into scale/shift)
__global__ __launch_bounds__(256) void dw_kernel(
    const float* __restrict__ x, const float* __restrict__ dww, const float* __restrict__ dwb,
    const float* __restrict__ g1, const float* __restrict__ b1,
    const float* __restrict__ m1, const float* __restrict__ v1,
    const float* __restrict__ pww, const float* __restrict__ pwb,
    const float* __restrict__ g2, const float* __restrict__ b2,
    const float* __restrict__ m2, const float* __restrict__ v2,
    u16* __restrict__ y, float* __restrict__ dwmaxp,
    u16* __restrict__ wb, float2* __restrict__ scsh)
{
    const int bid = blockIdx.x;
    const int t = threadIdx.x;

    if (bid >= 1792) {              // ---- prep path ----
        const int gid = (bid - 1792) * 256 + t;     // 0..16383
        const int base = gid * 8;                   // covers 131072 = COUT*CIN
        const float4 a = *(const float4*)(pww + base);
        const float4 b = *(const float4*)(pww + base + 4);
        union { u16 u[8]; s16x8 v; } pk;
        pk.u[0] = bf16_bits(a.x); pk.u[1] = bf16_bits(a.y);
        pk.u[2] = bf16_bits(a.z); pk.u[3] = bf16_bits(a.w);
        pk.u[4] = bf16_bits(b.x); pk.u[5] = bf16_bits(b.y);
        pk.u[6] = bf16_bits(b.z); pk.u[7] = bf16_bits(b.w);
        *(s16x8*)(wb + base) = pk.v;
        if (gid < COUT) {
            const float sc = g2[gid] * rsqrtf(v2[gid] + EPS);
            const float sh = fmaf(-m2[gid], sc, b2[gid]) + pwb[gid] * sc;
            scsh[gid] = make_float2(sc, sh);
        }
        return;
    }

    __shared__ float xs[32 * DPITCH];   // 72.2 KB: [c][local row 0..9][px]
    __shared__ float sm[256];

    const int n   = bid / 56;
    const int rem = bid % 56;
    const int hs  = rem >> 3;           // strip 0..6 (8 rows each)
    const int cg  = rem & 7;            // channel group 0..7 (32 ch each)

    const int g0     = hs * 8 - 1;                  // global row at local slot 0
    const int gstart = (g0 < 0) ? 0 : g0;
    const int nrows  = (hs == 0 || hs == 6) ? 9 : 10;
    const int dst0   = (hs == 0) ? 1 : 0;
    const int cnt4   = nrows * 14;                  // float4s per channel span (126 or 140)

    // zero clipped halo row
    if (hs == 0) {
        for (int i = t; i < 32 * 14; i += 256) {
            const int c = i / 14, j = i - c * 14;
            *(float4*)&xs[c * DPITCH + j * 4] = make_float4(0.f, 0.f, 0.f, 0.f);
        }
    } else if (hs == 6) {
        for (int i = t; i < 32 * 14; i += 256) {
            const int c = i / 14, j = i - c * 14;
            *(float4*)&xs[c * DPITCH + 9 * 56 + j * 4] = make_float4(0.f, 0.f, 0.f, 0.f);
        }
    }

    // async staging: 96 (channel, 64-float4-segment) jobs over 4 waves
    {
        const float* gbase = x + (size_t)(n * CIN + cg * 32) * HW + gstart * 56;
        const int w = t >> 6, lane = t & 63;
        for (int i = 0; i < 24; ++i) {
            const int j = w + 4 * i;           // 0..95
            const int c = j / 3, s = j - c * 3;
            const int i4 = s * 64 + lane;
            if (i4 < cnt4)
                async_copy16(&xs[c * DPITCH + dst0 * 56 + i4 * 4],
                             gbase + (size_t)c * HW + i4 * 4);
        }
    }
    __syncthreads();

    // compute: thread = (row r 0..7, channel c 0..31); all 256 active
    const int r = t >> 5;
    const int c = t & 31;
    float vmax = 0.f;
    {
        const int ch = cg * 32 + c;
        const float* wp = dww + ch * 9;
        const float w00 = wp[0], w01 = wp[1], w02 = wp[2];
        const float w10 = wp[3], w11 = wp[4], w12 = wp[5];
        const float w20 = wp[6], w21 = wp[7], w22 = wp[8];
        const float sc = g1[ch] * rsqrtf(v1[ch] + EPS);
        const float sh = fmaf(-m1[ch], sc, b1[ch]) + dwb[ch] * sc;

        const float* rm = &xs[c * DPITCH + r * 56];        // global row (hs*8+r)-1
        const float* r0 = rm + 56;
        const float* rp = rm + 112;
        const int grow = hs * 8 + r;
        u16* yo = y + (size_t)(n * HW + grow * 56) * CIN + ch;

        float4 cm = *(const float4*)rm;
        float4 c0 = *(const float4*)r0;
        float4 cp = *(const float4*)rp;
        float lm = 0.f, l0 = 0.f, lp = 0.f;

        for (int chk = 0; chk < 14; ++chk) {
            float4 nm, n0, np;
            if (chk < 13) {
                nm = *(const float4*)(rm + 4 * chk + 4);
                n0 = *(const float4*)(r0 + 4 * chk + 4);
                np = *(const float4*)(rp + 4 * chk + 4);
            } else {
                nm = n0 = np = make_float4(0.f, 0.f, 0.f, 0.f);
            }
            float s0 = w00*lm   + w01*cm.x + w02*cm.y
                     + w10*l0   + w11*c0.x + w12*c0.y
                     + w20*lp   + w21*cp.x + w22*cp.y;
            float s1 = w00*cm.x + w01*cm.y + w02*cm.z
                     + w10*c0.x + w11*c0.y + w12*c0.z
                     + w20*cp.x + w21*cp.y + w22*cp.z;
            float s2 = w00*cm.y + w01*cm.z + w02*cm.w
                     + w10*c0.y + w11*c0.z + w12*c0.w
                     + w20*cp.y + w21*cp.z + w22*cp.w;
            float s3 = w00*cm.z + w01*cm.w + w02*nm.x
                     + w10*c0.z + w11*c0.w + w12*n0.x
                     + w20*cp.z + w21*cp.w + w22*np.x;
            const float v0  = fmaxf(fmaf(s0, sc, sh), 0.f);
            const float v1s = fmaxf(fmaf(s1, sc, sh), 0.f);
            const float v2s = fmaxf(fmaf(s2, sc, sh), 0.f);
            const float v3  = fmaxf(fmaf(s3, sc, sh), 0.f);
            vmax = fmaxf(fmaxf(vmax, fmaxf(v0, v1s)), fmaxf(v2s, v3));
            yo[(4 * chk + 0) * CIN] = bf16_bits(v0);
            yo[(4 * chk + 1) * CIN] = bf16_bits(v1s);
            yo[(4 * chk + 2) * CIN] = bf16_bits(v2s);
            yo[(4 * chk + 3) * CIN] = bf16_bits(v3);
            lm = cm.w; l0 = c0.w; lp = cp.w;
            cm = nm; c0 = n0; cp = np;
        }
    }

    // per-channel partial max over the strip's 8 rows -> plain store (no atomics, no init)
    sm[t] = vmax;
    __syncthreads();
    if (t < 32) {
        float m = sm[t];
#pragma unroll
        for (int k = 1; k < 8; ++k) m = fmaxf(m, sm[t + 32 * k]);
        dwmaxp[(n * 7 + hs) * 256 + cg * 32 + t] = m;
    }
}

// ---------------- pw v4: bf16 MFMA GEMM, O=256 x HW=112, BK=32, 3-buffer counted-vmcnt pipeline ----------------
// 4 waves x 64 O-rows; per wave per K-step: exactly 6 global_load_lds (4 W + 2 Y), 11 ds_read, 28 MFMA.
// raw s_barrier + s_waitcnt vmcnt(6): loads stay in flight across barriers (never drained in main loop).
__global__ __launch_bounds__(256, 2) void pw_kernel(
    const u16* __restrict__ y, const u16* __restrict__ wb,
    const float2* __restrict__ scsh, const float* __restrict__ dwmaxp,
    float* __restrict__ out, float* __restrict__ omaxp)
{
    __shared__ __align__(16) u16 Wt[3][256 * 32];   // 48 KB: [o][k], pitch 64B
    __shared__ __align__(16) u16 Yt[3][128 * 32];   // 24 KB: [hw][k] (rows 112..127 = pad for uniform vmcnt)
    __shared__ __align__(16) u16 msk[CIN];          // 0xFFFF keep / 0 cut per k

    // 1792 = 8 XCD x 224; per XCD: ot fastest within (n,hwt) -> Y tile L2 reuse
    const int bid = blockIdx.x;
    const int g   = (bid & 7) * 224 + (bid >> 3);
    const int ot  = g & 1;
    const int r2  = g >> 1;
    const int hwt = r2 % 28;
    const int n   = r2 / 28;

    const int t = threadIdx.x;
    const int w = t >> 6;          // wave 0..3
    const int l = t & 63;
    const int lo = l & 15, hi = l >> 4;

    const int o_blk  = ot * 256;
    const int hw_blk = n * HW + hwt * 112;

    const u16* wg = wb + (size_t)(o_blk + w * 64 + (l >> 2)) * CIN + (l & 3) * 8;
    const u16* yg = y  + (size_t)(hw_blk + (l >> 2)) * CIN + (l & 3) * 8;

    // dw channel-cut mask: reduce 7 strip partials
    {
        float mm = dwmaxp[n * 7 * 256 + t];
#pragma unroll
        for (int s2 = 1; s2 < 7; ++s2) mm = fmaxf(mm, dwmaxp[(n * 7 + s2) * 256 + t]);
        msk[t] = (mm >= DW_TH) ? (u16)0xFFFFu : (u16)0u;
    }
    __syncthreads();    // msk visible to all waves; no pipeline loads issued yet

    f32x4 acc[4][7];
#pragma unroll
    for (int s = 0; s < 4; ++s)
#pragma unroll
        for (int j = 0; j < 7; ++j) acc[s][j] = (f32x4){0.f, 0.f, 0.f, 0.f};

    // per-wave stage of K-tile k0 into buffer buf: 4 W-loads + 2 Y-loads (Y group 7 duplicates group 6's src)
#define STAGE(buf, k0) do {                                                            \
        char* WtB_ = (char*)&Wt[buf][0];                                               \
        char* YtB_ = (char*)&Yt[buf][0];                                               \
        _Pragma("unroll")                                                              \
        for (int i_ = 0; i_ < 4; ++i_)                                                 \
            async_copy16(WtB_ + (w * 64 + i_ * 16) * 64 + l * 16,                      \
                         wg + (k0) + (size_t)(i_ * 16) * CIN);                         \
        const int j0_ = 2 * w;                                                         \
        async_copy16(YtB_ + (j0_ * 16) * 64 + l * 16,                                  \
                     yg + (k0) + (size_t)(j0_ * 16) * CIN);                            \
        const int j1_ = j0_ + 1, sj_ = (j1_ == 7) ? 6 : j1_;                           \
        async_copy16(YtB_ + (j1_ * 16) * 64 + l * 16,                                  \
                     yg + (k0) + (size_t)(sj_ * 16) * CIN);                            \
    } while (0)

    STAGE(0, 0);
    asm volatile("" ::: "memory");     // keep buf0's 6 loads older than buf1's in issue order
    STAGE(1, 32);

#pragma unroll
    for (int tk = 0; tk < 8; ++tk) {
        const int cur = tk % 3;
        // wait for this wave's K-tile tk loads (oldest 6); keep tk+1's 6 in flight
        if (tk < 7) asm volatile("s_waitcnt vmcnt(6)" ::: "memory");
        else        asm volatile("s_waitcnt vmcnt(0)" ::: "memory");
        __builtin_amdgcn_s_barrier();            // all waves' tile-tk loads landed; prev-step reads done
        __builtin_amdgcn_sched_barrier(0);       // no ds_read hoisting above the barrier
        if (tk < 6) { STAGE((tk + 2) % 3, (tk + 2) * 32); }   // overwrites buf read 2 steps ago

        const char* WtB = (const char*)&Wt[cur][0];
        const char* YtB = (const char*)&Yt[cur][0];
        const s16x8 m8 = *(const s16x8*)((const char*)msk + tk * 64 + hi * 16);

        s16x8 af[4], bf7[7];
#pragma unroll
        for (int s = 0; s < 4; ++s) {
            af[s] = *(const s16x8*)(WtB + (w * 64 + s * 16 + lo) * 64 + hi * 16);
            af[s] = af[s] & m8;    // zero cut channels (A-column zero == y-channel zero)
        }
#pragma unroll
        for (int j = 0; j < 7; ++j)
            bf7[j] = *(const s16x8*)(YtB + (j * 16 + lo) * 64 + hi * 16);

        __builtin_amdgcn_s_setprio(1);
#pragma unroll
        for (int s = 0; s < 4; ++s)
#pragma unroll
            for (int j = 0; j < 7; ++j)
                acc[s][j] = __builtin_amdgcn_mfma_f32_16x16x32_bf16(af[s], bf7[j], acc[s][j], 0, 0, 0);
        __builtin_amdgcn_s_setprio(0);
    }
#undef STAGE

    // epilogue: C/D layout col=lane&15 (hw), row=(lane>>4)*4+reg (o); partial max store (no atomics)
#pragma unroll
    for (int s = 0; s < 4; ++s) {
#pragma unroll
        for (int r = 0; r < 4; ++r) {
            const int o = o_blk + w * 64 + s * 16 + hi * 4 + r;
            const float2 ss = scsh[o];
            float m = 0.f;
            float* op = out + (size_t)(n * COUT + o) * HW + hwt * 112 + lo;
#pragma unroll
            for (int j = 0; j < 7; ++j) {
                const float v = fmaxf(fmaf(acc[s][j][r], ss.x, ss.y), 0.f);
                op[j * 16] = v;
                m = fmaxf(m, v);
            }
            m = fmaxf(m, __shfl_xor(m, 1));
            m = fmaxf(m, __shfl_xor(m, 2));
            m = fmaxf(m, __shfl_xor(m, 4));
            m = fmaxf(m, __shfl_xor(m, 8));
            if (lo == 0) omaxp[(size_t)(n * COUT + o) * 28 + hwt] = m;
        }
    }
}

// ---------------- pw channel cut: reduce 28 hw-tile partials, zero if below threshold ----------------
__global__ __launch_bounds__(64) void pwcut_kernel(const float* __restrict__ omaxp, float* __restrict__ out)
{
    const int b = blockIdx.x;   // n*COUT + o
    const int t = threadIdx.x;
    float m = (t < 28) ? omaxp[(size_t)b * 28 + t] : 0.f;
#pragma unroll
    for (int d = 1; d < 64; d <<= 1) m = fmaxf(m, __shfl_xor(m, d));
    if (m >= PW_TH) return;
    float4* p = (float4*)(out + (size_t)b * HW);
    const float4 z = make_float4(0.f, 0.f, 0.f, 0.f);
    for (int i = t; i < HW / 4; i += 64) p[i] = z;
}

extern "C" void kernel_launch(void* const* d_in, const int* in_sizes, int n_in,
                              void* d_out, int out_size, void* d_ws, size_t ws_size,
                              hipStream_t stream) {
    const float* x   = (const float*)d_in[0];
    const float* dww = (const float*)d_in[1];
    const float* dwb = (const float*)d_in[2];
    const float* g1  = (const float*)d_in[3];
    const float* b1  = (const float*)d_in[4];
    const float* m1  = (const float*)d_in[5];
    const float* v1  = (const float*)d_in[6];
    const float* pww = (const float*)d_in[7];
    const float* pwb = (const float*)d_in[8];
    const float* g2  = (const float*)d_in[9];
    const float* b2  = (const float*)d_in[10];
    const float* m2  = (const float*)d_in[11];
    const float* v2  = (const float*)d_in[12];
    float* out = (float*)d_out;

    // ws layout (no zero-init required anywhere):
    // [0, 1.8M)  omaxp   (16384 * 28 f32 partial maxes)
    // [2M, +224K) dwmaxp (32 * 7 * 256 f32 partial maxes)
    // [3M, +4K)  scsh
    // [4M, +256K) W bf16
    // [8M, +51.4M) y NHWC bf16
    float*  omaxp  = (float*)d_ws;
    float*  dwmaxp = (float*)((char*)d_ws + (2 << 20));
    float2* scsh   = (float2*)((char*)d_ws + (3 << 20));
    u16*    wbf    = (u16*)((char*)d_ws + (4 << 20));
    u16*    yv     = (u16*)((char*)d_ws + (8 << 20));

    dw_kernel<<<1792 + 64, 256, 0, stream>>>(x, dww, dwb, g1, b1, m1, v1,
                                             pww, pwb, g2, b2, m2, v2,
                                             yv, dwmaxp, wbf, scsh);
    pw_kernel<<<1792, 256, 0, stream>>>(yv, wbf, scsh, dwmaxp, out, omaxp);
    pwcut_kernel<<<NBATCH * COUT, 64, 0, stream>>>(omaxp, out);
}